// Round 15
// baseline (49.760 us; speedup 1.0000x reference)
//
#include <hip/hip_runtime.h>
#include <stdint.h>

#define B 256
#define DIM 512
#define TOPK 4096
#define MARGIN 0.2f
#define SC_AGENT __HIP_MEMORY_SCOPE_AGENT
#define PMAX 64
#define BUFCAP 60000u
#define FIX_SCALE 4294967296.0   /* 2^32 */

// ---------------- ws layout (u32 indices) ----------------
// ghA [0,2048)   gCnt 2048   cnt1 2049   gSum u64 @ u32 2050 (byte 8200)
// buf [2052, 62052)  (not zeroed)
// Dm  float[65536] @ u32 65536 (byte 262144)
#define WS_ZERO_WORDS 2052

__device__ __forceinline__ uint32_t ld_rlx32(const uint32_t* p) {
    return __hip_atomic_load(p, __ATOMIC_RELAXED, SC_AGENT);
}
__device__ __forceinline__ uint64_t ld_rlx64(const uint64_t* p) {
    return __hip_atomic_load(p, __ATOMIC_RELAXED, SC_AGENT);
}
__device__ __forceinline__ void st_rlx32(uint32_t* p, uint32_t v) {
    __hip_atomic_store(p, v, __ATOMIC_RELAXED, SC_AGENT);
}
__device__ __forceinline__ uint64_t fixv(float v) {
    return (uint64_t)((double)v * FIX_SCALE + 0.5);
}

// ================= z0: zero the protocol state (replaces hipMemsetAsync) ====
__global__ void __launch_bounds__(256, 1)
z0_zero(uint32_t* __restrict__ gws) {
    for (int i = threadIdx.x; i < WS_ZERO_WORDS; i += 256) gws[i] = 0u;
}

// Radix-select step over 256*PER buckets (LDS), descending. Thread tid owns
// chunk (255-tid); inclusive shuffle-scan over tid == suffix sums.
template <int PER>
__device__ void selstep(const uint32_t* h, uint32_t needed,
                        uint32_t* wtot, uint32_t* res, int tid) {
    const int chunk = 255 - tid;
    uint32_t vals[PER];
    uint32_t v = 0;
#pragma unroll
    for (int k = 0; k < PER; ++k) {
        vals[k] = h[chunk * PER + k];
        v += vals[k];
    }
    uint32_t s = v;
    const int lane = tid & 63, wv = tid >> 6;
#pragma unroll
    for (int d = 1; d < 64; d <<= 1) {
        uint32_t t = __shfl_up(s, d, 64);
        if (lane >= d) s += t;
    }
    if (lane == 63) wtot[wv] = s;
    __syncthreads();
    uint32_t off = 0;
    for (int w = 0; w < wv; ++w) off += wtot[w];
    s += off;                       // count in buckets >= chunk*PER
    const uint32_t excl = s - v;    // count strictly above own chunk
    if (excl < needed && needed <= s) {
        uint32_t cum = excl;
#pragma unroll
        for (int k = PER - 1; k >= 0; --k) {
            const uint32_t hv = vals[k];
            if (cum + hv >= needed) {
                res[0] = (uint32_t)(chunk * PER + k);
                res[1] = needed - cum;
                break;
            }
            cum += hv;
        }
    }
    __syncthreads();
}

// Shared helper: compact valid positives (p < q, same label) into pbase.
__device__ __forceinline__ int compact_pos(const float* sD, const int* sL,
                                           float* pbase, int* wcnt,
                                           int q, int tid, int lane, int wv) {
    const int lq = sL[q];
    const bool pred = (tid < q) && (sL[tid] == lq);
    const uint64_t mask = __ballot(pred);
    if (lane == 0) wcnt[wv] = __popcll(mask);
    __syncthreads();
    int off = 0;
    for (int w = 0; w < wv; ++w) off += wcnt[w];
    if (pred) {
        const int pos = off + __popcll(mask & ((1ull << lane) - 1));
        if (pos < PMAX) pbase[pos] = sD[tid] + MARGIN;
    }
    const int t = wcnt[0] + wcnt[1] + wcnt[2] + wcnt[3];
    return t < PMAX ? t : PMAX;
}

// ================= k1: D rows + level-1 histogram =================
__global__ void __launch_bounds__(256, 1)
k1_dist_hist(const float* __restrict__ x, const int* __restrict__ lab,
             uint32_t* __restrict__ gws, float* __restrict__ Dm) {
    uint32_t* ghA = gws;
    __shared__ uint32_t sh[4][2048];              // 32 KB wave-privatized hists
    __shared__ float    sD[B];
    __shared__ int      sL[B];
    __shared__ float    pbase[PMAX];
    __shared__ int      wcnt[4];

    const int q = blockIdx.x, tid = threadIdx.x;
    const int lane = tid & 63, wv = tid >> 6;

    // D row q: per-thread-row, xi staged in LDS (alias sh)
    {
        float* xi = (float*)sh;
        for (int k = tid; k < DIM; k += 256) xi[k] = x[q * DIM + k];
        sL[tid] = lab[tid];
        __syncthreads();
        const float4* xj4 = (const float4*)(x + tid * DIM);
        float acc = 0.f;
#pragma unroll 4
        for (int k4 = 0; k4 < DIM / 4; ++k4) {
            float4 b = xj4[k4];
            float d0 = xi[k4 * 4 + 0] - b.x;
            float d1 = xi[k4 * 4 + 1] - b.y;
            float d2 = xi[k4 * 4 + 2] - b.z;
            float d3 = xi[k4 * 4 + 3] - b.w;
            acc += d0 * d0 + d1 * d1 + d2 * d2 + d3 * d3;
        }
        sD[tid] = acc;
        Dm[q * B + tid] = acc;                    // for k2
    }
    __syncthreads();                              // xi reads done; sh reusable

    for (int i = tid; i < 4 * 2048; i += 256) ((uint32_t*)sh)[i] = 0;
    const int pcnt = compact_pos(sD, sL, pbase, wcnt, q, tid, lane, wv);
    __syncthreads();
    const bool  nvalid = (sL[tid] != sL[q]);
    const float dqn    = sD[tid];

    // hist over bits[31:21]; zeros counted in registers, wave-private
    {
        uint32_t zc = 0;
        if (nvalid) {
            for (int ip = 0; ip < pcnt; ++ip) {
                const float v = fmaxf(pbase[ip] - dqn, 0.0f);
                if (v == 0.0f) { ++zc; continue; }      // bucket 0; no atomic
                atomicAdd(&sh[wv][__float_as_uint(v) >> 21], 1u);
            }
        }
#pragma unroll
        for (int off = 32; off > 0; off >>= 1) zc += __shfl_down(zc, off, 64);
        if (lane == 0 && zc) atomicAdd(&sh[wv][0], zc);
    }
    __syncthreads();
    for (int i = tid; i < 2048; i += 256) {
        const uint32_t c = sh[0][i] + sh[1][i] + sh[2][i] + sh[3][i];
        if (c) atomicAdd(&ghA[i], c);
    }
}

// ================= k2: select + sum + finalize =================
__global__ void __launch_bounds__(256, 1)
k2_select_sum(const int* __restrict__ lab, uint32_t* __restrict__ gws,
              const float* __restrict__ Dm, float* __restrict__ out) {
    uint32_t* ghA  = gws;
    uint32_t* gCnt = gws + 2048;
    uint32_t* cnt1 = gws + 2049;
    uint64_t* gSum = (uint64_t*)(gws + 2050);
    uint32_t* buf  = gws + 2052;

    __shared__ uint32_t sh[2048];                 // select copy / finalizer hist
    __shared__ unsigned long long ssum[2048];
    __shared__ float    sD[B];
    __shared__ int      sL[B];
    __shared__ float    pbase[PMAX];
    __shared__ int      wcnt[4];
    __shared__ uint32_t wtot[4];
    __shared__ uint32_t res[2];
    __shared__ unsigned long long usum[4];
    __shared__ unsigned long long sAcc2;
    __shared__ uint32_t sBase;
    __shared__ int      sFin;

    const int q = blockIdx.x, tid = threadIdx.x;
    const int lane = tid & 63, wv = tid >> 6;

    // reload D row + labels; copy ghA to LDS with plain cached loads
    sD[tid] = Dm[q * B + tid];
    sL[tid] = lab[tid];
    for (int i = tid; i < 2048; i += 256) sh[i] = ghA[i];
    __syncthreads();
    const int pcnt = compact_pos(sD, sL, pbase, wcnt, q, tid, lane, wv);
    __syncthreads();
    const bool  nvalid = (sL[tid] != sL[q]);
    const float dqn    = sD[tid];

    // select of s0 (redundant per block, on LDS copy)
    selstep<8>(sh, (uint32_t)TOPK, wtot, res, tid);
    const uint32_t s0      = res[0];
    const uint32_t needed0 = res[1];

    // phase 2: register sum above s0 + append in-bucket values
    uint64_t sumA = 0;
    uint32_t cin  = 0;
    if (nvalid) {
        for (int ip = 0; ip < pcnt; ++ip) {
            const float v = fmaxf(pbase[ip] - dqn, 0.0f);
            const uint32_t bk = __float_as_uint(v) >> 21;
            if (bk > s0) sumA += fixv(v);
            else if (bk == s0) ++cin;
        }
    }
    {
        uint32_t inc = cin;
#pragma unroll
        for (int d = 1; d < 64; d <<= 1) {
            uint32_t t2 = __shfl_up(inc, d, 64);
            if (lane >= d) inc += t2;
        }
        if (lane == 63) wtot[wv] = inc;
        __syncthreads();
        uint32_t woff = 0;
        for (int w = 0; w < wv; ++w) woff += wtot[w];
        const uint32_t myoff = woff + inc - cin;
        if (tid == 0) {
            const uint32_t tot = wtot[0] + wtot[1] + wtot[2] + wtot[3];
            sBase = tot ? atomicAdd(gCnt, tot) : 0u;
        }
        __syncthreads();
        if (cin) {
            uint32_t o = sBase + myoff;
            for (int ip = 0; ip < pcnt; ++ip) {
                const uint32_t bits =
                    __float_as_uint(fmaxf(pbase[ip] - dqn, 0.0f));
                if ((bits >> 21) == s0) {
                    if (o < BUFCAP) st_rlx32(&buf[o], bits);
                    ++o;
                }
            }
        }
    }
    // block-reduce sumA -> one gSum RMW per block
#pragma unroll
    for (int off = 32; off > 0; off >>= 1)
        sumA += __shfl_down((unsigned long long)sumA, off, 64);
    if (lane == 0) usum[wv] = sumA;
    __syncthreads();
    if (tid == 0) {
        const unsigned long long bt = usum[0] + usum[1] + usum[2] + usum[3];
        if (bt) atomicAdd((unsigned long long*)gSum, bt);
    }
    __syncthreads();   // drain all waves' global ops before arrival
    if (tid == 0) {
        const uint32_t old =
            __hip_atomic_fetch_add(cnt1, 1u, __ATOMIC_ACQ_REL, SC_AGENT);
        sFin = (old == B - 1) ? 1 : 0;
    }
    __syncthreads();
    if (!sFin) return;   // 255 blocks exit; no spinning

    // ---------------- finalizer (last arriver) ----------------
    const uint32_t nbuf = min(ld_rlx32(gCnt), BUFCAP);

    // level 2: bits[20:10] count+sum hists from buf
    for (int i = tid; i < 2048; i += 256) { sh[i] = 0; ssum[i] = 0ull; }
    __syncthreads();
    for (uint32_t i = (uint32_t)tid; i < nbuf; i += 256) {
        const uint32_t b = ld_rlx32(&buf[i]);
        const uint32_t b2 = (b >> 10) & 0x7FFu;
        atomicAdd(&sh[b2], 1u);
        atomicAdd(&ssum[b2], (unsigned long long)fixv(__uint_as_float(b)));
    }
    __syncthreads();
    selstep<8>(sh, needed0, wtot, res, tid);
    const uint32_t s1      = res[0];
    const uint32_t needed1 = res[1];
    {
        uint64_t sb = 0;
#pragma unroll
        for (int k = 0; k < 8; ++k) {
            const uint32_t b = (uint32_t)tid * 8u + (uint32_t)k;
            if (b > s1) sb += ssum[b];
        }
#pragma unroll
        for (int off = 32; off > 0; off >>= 1)
            sb += __shfl_down((unsigned long long)sb, off, 64);
        if (lane == 0) usum[wv] = sb;
        __syncthreads();
        if (tid == 0) sAcc2 = usum[0] + usum[1] + usum[2] + usum[3];
    }
    __syncthreads();

    // level 3: bits[9:0] within (s0,s1)
    for (int i = tid; i < 1024; i += 256) { sh[i] = 0; ssum[i] = 0ull; }
    __syncthreads();
    for (uint32_t i = (uint32_t)tid; i < nbuf; i += 256) {
        const uint32_t b = ld_rlx32(&buf[i]);
        if (((b >> 10) & 0x7FFu) == s1) {
            const uint32_t b3 = b & 0x3FFu;
            atomicAdd(&sh[b3], 1u);
            atomicAdd(&ssum[b3], (unsigned long long)fixv(__uint_as_float(b)));
        }
    }
    __syncthreads();
    selstep<4>(sh, needed1, wtot, res, tid);
    const uint32_t s2      = res[0];
    const uint32_t needed2 = res[1];
    const uint32_t T = (s0 << 21) | (s1 << 10) | s2;
    {
        uint64_t sb = 0;
#pragma unroll
        for (int k = 0; k < 4; ++k) {
            const uint32_t b = (uint32_t)tid * 4u + (uint32_t)k;
            if (b > s2) sb += ssum[b];
        }
#pragma unroll
        for (int off = 32; off > 0; off >>= 1)
            sb += __shfl_down((unsigned long long)sb, off, 64);
        if (lane == 0) usum[wv] = sb;
        __syncthreads();
        if (tid == 0) {
            const uint64_t total =
                usum[0] + usum[1] + usum[2] + usum[3] + sAcc2 + ld_rlx64(gSum);
            const double tval = (double)__uint_as_float(T);
            const double loss = ((double)total * (1.0 / FIX_SCALE) +
                                 (double)needed2 * tval) / (double)TOPK;
            out[0] = (float)loss;
        }
    }
}

extern "C" void kernel_launch(void* const* d_in, const int* in_sizes, int n_in,
                              void* d_out, int out_size, void* d_ws, size_t ws_size,
                              hipStream_t stream) {
    const float* x   = (const float*)d_in[0];
    const int*   lab = (const int*)d_in[1];
    float*       out = (float*)d_out;
    uint32_t*    gws = (uint32_t*)d_ws;
    float*       Dm  = (float*)((char*)d_ws + 262144);

    z0_zero<<<1, 256, 0, stream>>>(gws);
    k1_dist_hist<<<B, 256, 0, stream>>>(x, lab, gws, Dm);
    k2_select_sum<<<B, 256, 0, stream>>>(lab, gws, Dm, out);
}

// Round 16
// 44.790 us; speedup vs baseline: 1.1110x; 1.1110x over previous
//
#include <hip/hip_runtime.h>
#include <stdint.h>

#define B 256
#define DIM 512
#define TOPK 4096
#define MARGIN 0.2f
#define SC_AGENT __HIP_MEMORY_SCOPE_AGENT
#define PMAX 64
#define BUFCAP 60000u
#define FIX_SCALE 4294967296.0   /* 2^32 */
#define MAGIC64 0x9E3779B97F4A7C15ull

// ---------------- ws layout (u32 indices) ----------------
// ghA [0,2048)   gCnt 2048   cnt1 2049   gSum u64 @ u32 2050 (byte 8200)
// gReady u64 @ u32 2052 (byte 8208)   buf [2054, 62054)
// Dm  float[65536] @ byte 262144
// All protocol state zeroed by k1 block 0 each call (no init node).

__device__ __forceinline__ uint32_t ld_rlx32(const uint32_t* p) {
    return __hip_atomic_load(p, __ATOMIC_RELAXED, SC_AGENT);
}
__device__ __forceinline__ uint64_t ld_rlx64(const uint64_t* p) {
    return __hip_atomic_load(p, __ATOMIC_RELAXED, SC_AGENT);
}
__device__ __forceinline__ void st_rlx32(uint32_t* p, uint32_t v) {
    __hip_atomic_store(p, v, __ATOMIC_RELAXED, SC_AGENT);
}
__device__ __forceinline__ uint64_t fixv(float v) {
    return (uint64_t)((double)v * FIX_SCALE + 0.5);
}

// Radix-select step over 256*PER buckets (LDS), descending. Thread tid owns
// chunk (255-tid); inclusive shuffle-scan over tid == suffix sums.
template <int PER>
__device__ void selstep(const uint32_t* h, uint32_t needed,
                        uint32_t* wtot, uint32_t* res, int tid) {
    const int chunk = 255 - tid;
    uint32_t vals[PER];
    uint32_t v = 0;
#pragma unroll
    for (int k = 0; k < PER; ++k) {
        vals[k] = h[chunk * PER + k];
        v += vals[k];
    }
    uint32_t s = v;
    const int lane = tid & 63, wv = tid >> 6;
#pragma unroll
    for (int d = 1; d < 64; d <<= 1) {
        uint32_t t = __shfl_up(s, d, 64);
        if (lane >= d) s += t;
    }
    if (lane == 63) wtot[wv] = s;
    __syncthreads();
    uint32_t off = 0;
    for (int w = 0; w < wv; ++w) off += wtot[w];
    s += off;                       // count in buckets >= chunk*PER
    const uint32_t excl = s - v;    // count strictly above own chunk
    if (excl < needed && needed <= s) {
        uint32_t cum = excl;
#pragma unroll
        for (int k = PER - 1; k >= 0; --k) {
            const uint32_t hv = vals[k];
            if (cum + hv >= needed) {
                res[0] = (uint32_t)(chunk * PER + k);
                res[1] = needed - cum;
                break;
            }
            cum += hv;
        }
    }
    __syncthreads();
}

// Shared helper: compact valid positives (p < q, same label) into pbase.
__device__ __forceinline__ int compact_pos(const float* sD, const int* sL,
                                           float* pbase, int* wcnt,
                                           int q, int tid, int lane, int wv) {
    const int lq = sL[q];
    const bool pred = (tid < q) && (sL[tid] == lq);
    const uint64_t mask = __ballot(pred);
    if (lane == 0) wcnt[wv] = __popcll(mask);
    __syncthreads();
    int off = 0;
    for (int w = 0; w < wv; ++w) off += wcnt[w];
    if (pred) {
        const int pos = off + __popcll(mask & ((1ull << lane) - 1));
        if (pos < PMAX) pbase[pos] = sD[tid] + MARGIN;
    }
    const int t = wcnt[0] + wcnt[1] + wcnt[2] + wcnt[3];
    return t < PMAX ? t : PMAX;
}

// ================= k1: init (block 0) + D rows + level-1 histogram =========
__global__ void __launch_bounds__(256, 1)
k1_dist_hist(const float* __restrict__ x, const int* __restrict__ lab,
             uint32_t* __restrict__ gws, float* __restrict__ Dm) {
    uint32_t* ghA    = gws;
    uint64_t* gReady = (uint64_t*)(gws + 2052);
    __shared__ uint32_t sh[4][2048];              // 32 KB wave-privatized hists
    __shared__ float    sD[B];
    __shared__ int      sL[B];
    __shared__ float    pbase[PMAX];
    __shared__ int      wcnt[4];

    const int q = blockIdx.x, tid = threadIdx.x;
    const int lane = tid & 63, wv = tid >> 6;

    // ---- block 0: zero protocol state, then release-publish MAGIC ----
    if (q == 0) {
        for (int i = tid; i < 2050; i += 256) st_rlx32(&gws[i], 0u);  // ghA,gCnt,cnt1
        if (tid == 0) __hip_atomic_store((uint64_t*)(gws + 2050), 0ull,
                                         __ATOMIC_RELAXED, SC_AGENT); // gSum
        __syncthreads();
        if (tid == 0)
            __hip_atomic_store(gReady, MAGIC64, __ATOMIC_RELEASE, SC_AGENT);
    }

    // D row q: per-thread-row, xi staged in LDS (alias sh)
    {
        float* xi = (float*)sh;
        for (int k = tid; k < DIM; k += 256) xi[k] = x[q * DIM + k];
        sL[tid] = lab[tid];
        __syncthreads();
        const float4* xj4 = (const float4*)(x + tid * DIM);
        float acc = 0.f;
#pragma unroll 4
        for (int k4 = 0; k4 < DIM / 4; ++k4) {
            float4 b = xj4[k4];
            float d0 = xi[k4 * 4 + 0] - b.x;
            float d1 = xi[k4 * 4 + 1] - b.y;
            float d2 = xi[k4 * 4 + 2] - b.z;
            float d3 = xi[k4 * 4 + 3] - b.w;
            acc += d0 * d0 + d1 * d1 + d2 * d2 + d3 * d3;
        }
        sD[tid] = acc;
        Dm[q * B + tid] = acc;                    // for k2
    }
    __syncthreads();                              // xi reads done; sh reusable

    for (int i = tid; i < 4 * 2048; i += 256) ((uint32_t*)sh)[i] = 0;
    const int pcnt = compact_pos(sD, sL, pbase, wcnt, q, tid, lane, wv);
    __syncthreads();
    const bool  nvalid = (sL[tid] != sL[q]);
    const float dqn    = sD[tid];

    // hist over bits[31:21]; zeros counted in registers, wave-private
    {
        uint32_t zc = 0;
        if (nvalid) {
            for (int ip = 0; ip < pcnt; ++ip) {
                const float v = fmaxf(pbase[ip] - dqn, 0.0f);
                if (v == 0.0f) { ++zc; continue; }      // bucket 0; no atomic
                atomicAdd(&sh[wv][__float_as_uint(v) >> 21], 1u);
            }
        }
#pragma unroll
        for (int off = 32; off > 0; off >>= 1) zc += __shfl_down(zc, off, 64);
        if (lane == 0 && zc) atomicAdd(&sh[wv][0], zc);
    }
    __syncthreads();

    // ---- wait for init (acquire) before merging into ghA ----
    if (tid == 0) {
        while (__hip_atomic_load(gReady, __ATOMIC_ACQUIRE, SC_AGENT) != MAGIC64)
            __builtin_amdgcn_s_sleep(2);
    }
    __syncthreads();

    for (int i = tid; i < 2048; i += 256) {
        const uint32_t c = sh[0][i] + sh[1][i] + sh[2][i] + sh[3][i];
        if (c) atomicAdd(&ghA[i], c);
    }
}

// ================= k2: select + sum + finalize =================
__global__ void __launch_bounds__(256, 1)
k2_select_sum(const int* __restrict__ lab, uint32_t* __restrict__ gws,
              const float* __restrict__ Dm, float* __restrict__ out) {
    uint32_t* ghA  = gws;
    uint32_t* gCnt = gws + 2048;
    uint32_t* cnt1 = gws + 2049;
    uint64_t* gSum = (uint64_t*)(gws + 2050);
    uint32_t* buf  = gws + 2054;

    __shared__ uint32_t sh[2048];                 // select copy / finalizer hist
    __shared__ unsigned long long ssum[2048];
    __shared__ float    sD[B];
    __shared__ int      sL[B];
    __shared__ float    pbase[PMAX];
    __shared__ int      wcnt[4];
    __shared__ uint32_t wtot[4];
    __shared__ uint32_t res[2];
    __shared__ unsigned long long usum[4];
    __shared__ unsigned long long sAcc2;
    __shared__ uint32_t sBase;
    __shared__ int      sFin;

    const int q = blockIdx.x, tid = threadIdx.x;
    const int lane = tid & 63, wv = tid >> 6;

    // disarm init flag for the next graph replay (k1 re-arms it)
    if (q == 0 && tid == 0)
        __hip_atomic_store((uint64_t*)(gws + 2052), 0ull,
                           __ATOMIC_RELAXED, SC_AGENT);

    // reload D row + labels; copy ghA to LDS with plain cached loads
    sD[tid] = Dm[q * B + tid];
    sL[tid] = lab[tid];
    for (int i = tid; i < 2048; i += 256) sh[i] = ghA[i];
    __syncthreads();
    const int pcnt = compact_pos(sD, sL, pbase, wcnt, q, tid, lane, wv);
    __syncthreads();
    const bool  nvalid = (sL[tid] != sL[q]);
    const float dqn    = sD[tid];

    // select of s0 (redundant per block, on LDS copy)
    selstep<8>(sh, (uint32_t)TOPK, wtot, res, tid);
    const uint32_t s0      = res[0];
    const uint32_t needed0 = res[1];

    // phase 2: register sum above s0 + append in-bucket values
    uint64_t sumA = 0;
    uint32_t cin  = 0;
    if (nvalid) {
        for (int ip = 0; ip < pcnt; ++ip) {
            const float v = fmaxf(pbase[ip] - dqn, 0.0f);
            const uint32_t bk = __float_as_uint(v) >> 21;
            if (bk > s0) sumA += fixv(v);
            else if (bk == s0) ++cin;
        }
    }
    {
        uint32_t inc = cin;
#pragma unroll
        for (int d = 1; d < 64; d <<= 1) {
            uint32_t t2 = __shfl_up(inc, d, 64);
            if (lane >= d) inc += t2;
        }
        if (lane == 63) wtot[wv] = inc;
        __syncthreads();
        uint32_t woff = 0;
        for (int w = 0; w < wv; ++w) woff += wtot[w];
        const uint32_t myoff = woff + inc - cin;
        if (tid == 0) {
            const uint32_t tot = wtot[0] + wtot[1] + wtot[2] + wtot[3];
            sBase = tot ? atomicAdd(gCnt, tot) : 0u;
        }
        __syncthreads();
        if (cin) {
            uint32_t o = sBase + myoff;
            for (int ip = 0; ip < pcnt; ++ip) {
                const uint32_t bits =
                    __float_as_uint(fmaxf(pbase[ip] - dqn, 0.0f));
                if ((bits >> 21) == s0) {
                    if (o < BUFCAP) st_rlx32(&buf[o], bits);
                    ++o;
                }
            }
        }
    }
    // block-reduce sumA -> one gSum RMW per block
#pragma unroll
    for (int off = 32; off > 0; off >>= 1)
        sumA += __shfl_down((unsigned long long)sumA, off, 64);
    if (lane == 0) usum[wv] = sumA;
    __syncthreads();
    if (tid == 0) {
        const unsigned long long bt = usum[0] + usum[1] + usum[2] + usum[3];
        if (bt) atomicAdd((unsigned long long*)gSum, bt);
    }
    __syncthreads();   // drain all waves' global ops before arrival
    if (tid == 0) {
        const uint32_t old =
            __hip_atomic_fetch_add(cnt1, 1u, __ATOMIC_ACQ_REL, SC_AGENT);
        sFin = (old == B - 1) ? 1 : 0;
    }
    __syncthreads();
    if (!sFin) return;   // 255 blocks exit; no spinning

    // ---------------- finalizer (last arriver) ----------------
    const uint32_t nbuf = min(ld_rlx32(gCnt), BUFCAP);

    // level 2: bits[20:10] count+sum hists from buf
    for (int i = tid; i < 2048; i += 256) { sh[i] = 0; ssum[i] = 0ull; }
    __syncthreads();
    for (uint32_t i = (uint32_t)tid; i < nbuf; i += 256) {
        const uint32_t b = ld_rlx32(&buf[i]);
        const uint32_t b2 = (b >> 10) & 0x7FFu;
        atomicAdd(&sh[b2], 1u);
        atomicAdd(&ssum[b2], (unsigned long long)fixv(__uint_as_float(b)));
    }
    __syncthreads();
    selstep<8>(sh, needed0, wtot, res, tid);
    const uint32_t s1      = res[0];
    const uint32_t needed1 = res[1];
    {
        uint64_t sb = 0;
#pragma unroll
        for (int k = 0; k < 8; ++k) {
            const uint32_t b = (uint32_t)tid * 8u + (uint32_t)k;
            if (b > s1) sb += ssum[b];
        }
#pragma unroll
        for (int off = 32; off > 0; off >>= 1)
            sb += __shfl_down((unsigned long long)sb, off, 64);
        if (lane == 0) usum[wv] = sb;
        __syncthreads();
        if (tid == 0) sAcc2 = usum[0] + usum[1] + usum[2] + usum[3];
    }
    __syncthreads();

    // level 3: bits[9:0] within (s0,s1)
    for (int i = tid; i < 1024; i += 256) { sh[i] = 0; ssum[i] = 0ull; }
    __syncthreads();
    for (uint32_t i = (uint32_t)tid; i < nbuf; i += 256) {
        const uint32_t b = ld_rlx32(&buf[i]);
        if (((b >> 10) & 0x7FFu) == s1) {
            const uint32_t b3 = b & 0x3FFu;
            atomicAdd(&sh[b3], 1u);
            atomicAdd(&ssum[b3], (unsigned long long)fixv(__uint_as_float(b)));
        }
    }
    __syncthreads();
    selstep<4>(sh, needed1, wtot, res, tid);
    const uint32_t s2      = res[0];
    const uint32_t needed2 = res[1];
    const uint32_t T = (s0 << 21) | (s1 << 10) | s2;
    {
        uint64_t sb = 0;
#pragma unroll
        for (int k = 0; k < 4; ++k) {
            const uint32_t b = (uint32_t)tid * 4u + (uint32_t)k;
            if (b > s2) sb += ssum[b];
        }
#pragma unroll
        for (int off = 32; off > 0; off >>= 1)
            sb += __shfl_down((unsigned long long)sb, off, 64);
        if (lane == 0) usum[wv] = sb;
        __syncthreads();
        if (tid == 0) {
            const uint64_t total =
                usum[0] + usum[1] + usum[2] + usum[3] + sAcc2 + ld_rlx64(gSum);
            const double tval = (double)__uint_as_float(T);
            const double loss = ((double)total * (1.0 / FIX_SCALE) +
                                 (double)needed2 * tval) / (double)TOPK;
            out[0] = (float)loss;
        }
    }
}

extern "C" void kernel_launch(void* const* d_in, const int* in_sizes, int n_in,
                              void* d_out, int out_size, void* d_ws, size_t ws_size,
                              hipStream_t stream) {
    const float* x   = (const float*)d_in[0];
    const int*   lab = (const int*)d_in[1];
    float*       out = (float*)d_out;
    uint32_t*    gws = (uint32_t*)d_ws;
    float*       Dm  = (float*)((char*)d_ws + 262144);

    k1_dist_hist<<<B, 256, 0, stream>>>(x, lab, gws, Dm);
    k2_select_sum<<<B, 256, 0, stream>>>(lab, gws, Dm, out);
}

// Round 17
// 43.986 us; speedup vs baseline: 1.1313x; 1.0183x over previous
//
#include <hip/hip_runtime.h>
#include <stdint.h>

#define B 256
#define DIM 512
#define TOPK 4096
#define MARGIN 0.2f
#define SC_AGENT __HIP_MEMORY_SCOPE_AGENT
#define PMAX 64
#define BUFCAP 60000u
#define FIX_SCALE 4294967296.0   /* 2^32 */
#define MAGIC64 0x9E3779B97F4A7C15ull

// ---------------- ws layout (u32 indices) ----------------
// ghA [0,2048)   gCnt 2048   part u64[256] @ u32 2050 (byte 8200, 8-aligned)
// gF2 [2562,2818)   gReady u64 @ u32 2818 (byte 11272, 8-aligned)
// buf [2820, 62820)
// Dm  float[65536] @ byte 262144
// k1 block 0 zeroes ghA,gCnt,gF2 each call; part overwritten by every block.

__device__ __forceinline__ uint32_t ld_rlx32(const uint32_t* p) {
    return __hip_atomic_load(p, __ATOMIC_RELAXED, SC_AGENT);
}
__device__ __forceinline__ uint64_t ld_rlx64(const uint64_t* p) {
    return __hip_atomic_load(p, __ATOMIC_RELAXED, SC_AGENT);
}
__device__ __forceinline__ void st_rlx32(uint32_t* p, uint32_t v) {
    __hip_atomic_store(p, v, __ATOMIC_RELAXED, SC_AGENT);
}
__device__ __forceinline__ void st_rlx64(uint64_t* p, uint64_t v) {
    __hip_atomic_store(p, v, __ATOMIC_RELAXED, SC_AGENT);
}
__device__ __forceinline__ uint64_t fixv(float v) {
    return (uint64_t)((double)v * FIX_SCALE + 0.5);
}

// Radix-select step over 256*PER buckets (LDS), descending. Thread tid owns
// chunk (255-tid); inclusive shuffle-scan over tid == suffix sums.
template <int PER>
__device__ void selstep(const uint32_t* h, uint32_t needed,
                        uint32_t* wtot, uint32_t* res, int tid) {
    const int chunk = 255 - tid;
    uint32_t vals[PER];
    uint32_t v = 0;
#pragma unroll
    for (int k = 0; k < PER; ++k) {
        vals[k] = h[chunk * PER + k];
        v += vals[k];
    }
    uint32_t s = v;
    const int lane = tid & 63, wv = tid >> 6;
#pragma unroll
    for (int d = 1; d < 64; d <<= 1) {
        uint32_t t = __shfl_up(s, d, 64);
        if (lane >= d) s += t;
    }
    if (lane == 63) wtot[wv] = s;
    __syncthreads();
    uint32_t off = 0;
    for (int w = 0; w < wv; ++w) off += wtot[w];
    s += off;                       // count in buckets >= chunk*PER
    const uint32_t excl = s - v;    // count strictly above own chunk
    if (excl < needed && needed <= s) {
        uint32_t cum = excl;
#pragma unroll
        for (int k = PER - 1; k >= 0; --k) {
            const uint32_t hv = vals[k];
            if (cum + hv >= needed) {
                res[0] = (uint32_t)(chunk * PER + k);
                res[1] = needed - cum;
                break;
            }
            cum += hv;
        }
    }
    __syncthreads();
}

// Shared helper: compact valid positives (p < q, same label) into pbase.
__device__ __forceinline__ int compact_pos(const float* sD, const int* sL,
                                           float* pbase, int* wcnt,
                                           int q, int tid, int lane, int wv) {
    const int lq = sL[q];
    const bool pred = (tid < q) && (sL[tid] == lq);
    const uint64_t mask = __ballot(pred);
    if (lane == 0) wcnt[wv] = __popcll(mask);
    __syncthreads();
    int off = 0;
    for (int w = 0; w < wv; ++w) off += wcnt[w];
    if (pred) {
        const int pos = off + __popcll(mask & ((1ull << lane) - 1));
        if (pos < PMAX) pbase[pos] = sD[tid] + MARGIN;
    }
    const int t = wcnt[0] + wcnt[1] + wcnt[2] + wcnt[3];
    return t < PMAX ? t : PMAX;
}

// ================= k1: init (block 0) + D rows + level-1 histogram =========
__global__ void __launch_bounds__(256, 1)
k1_dist_hist(const float* __restrict__ x, const int* __restrict__ lab,
             uint32_t* __restrict__ gws, float* __restrict__ Dm) {
    uint32_t* ghA    = gws;
    uint64_t* gReady = (uint64_t*)(gws + 2818);
    __shared__ uint32_t sh[4][2048];              // 32 KB wave-privatized hists
    __shared__ float    sD[B];
    __shared__ int      sL[B];
    __shared__ float    pbase[PMAX];
    __shared__ int      wcnt[4];

    const int q = blockIdx.x, tid = threadIdx.x;
    const int lane = tid & 63, wv = tid >> 6;

    // ---- block 0: zero protocol state, then release-publish MAGIC ----
    if (q == 0) {
        for (int i = tid; i < 2049; i += 256) st_rlx32(&gws[i], 0u);   // ghA,gCnt
        if (tid < 256) st_rlx32(&gws[2562 + tid], 0u);                  // gF2
        __syncthreads();
        if (tid == 0)
            __hip_atomic_store(gReady, MAGIC64, __ATOMIC_RELEASE, SC_AGENT);
    }

    // D row q: per-thread-row, xi staged in LDS (alias sh)
    {
        float* xi = (float*)sh;
        for (int k = tid; k < DIM; k += 256) xi[k] = x[q * DIM + k];
        sL[tid] = lab[tid];
        __syncthreads();
        const float4* xj4 = (const float4*)(x + tid * DIM);
        float acc = 0.f;
#pragma unroll 4
        for (int k4 = 0; k4 < DIM / 4; ++k4) {
            float4 b = xj4[k4];
            float d0 = xi[k4 * 4 + 0] - b.x;
            float d1 = xi[k4 * 4 + 1] - b.y;
            float d2 = xi[k4 * 4 + 2] - b.z;
            float d3 = xi[k4 * 4 + 3] - b.w;
            acc += d0 * d0 + d1 * d1 + d2 * d2 + d3 * d3;
        }
        sD[tid] = acc;
        Dm[q * B + tid] = acc;                    // for k2
    }
    __syncthreads();                              // xi reads done; sh reusable

    for (int i = tid; i < 4 * 2048; i += 256) ((uint32_t*)sh)[i] = 0;
    const int pcnt = compact_pos(sD, sL, pbase, wcnt, q, tid, lane, wv);
    __syncthreads();
    const bool  nvalid = (sL[tid] != sL[q]);
    const float dqn    = sD[tid];

    // hist over bits[31:21]; zeros counted in registers, wave-private
    {
        uint32_t zc = 0;
        if (nvalid) {
            for (int ip = 0; ip < pcnt; ++ip) {
                const float v = fmaxf(pbase[ip] - dqn, 0.0f);
                if (v == 0.0f) { ++zc; continue; }      // bucket 0; no atomic
                atomicAdd(&sh[wv][__float_as_uint(v) >> 21], 1u);
            }
        }
#pragma unroll
        for (int off = 32; off > 0; off >>= 1) zc += __shfl_down(zc, off, 64);
        if (lane == 0 && zc) atomicAdd(&sh[wv][0], zc);
    }
    __syncthreads();

    // ---- wait for init (acquire) before merging into ghA ----
    if (tid == 0) {
        while (__hip_atomic_load(gReady, __ATOMIC_ACQUIRE, SC_AGENT) != MAGIC64)
            __builtin_amdgcn_s_sleep(2);
    }
    __syncthreads();

    for (int i = tid; i < 2048; i += 256) {
        const uint32_t c = sh[0][i] + sh[1][i] + sh[2][i] + sh[3][i];
        if (c) atomicAdd(&ghA[i], c);
    }
}

// ================= k2: select + sum + finalize (block 255) =================
__global__ void __launch_bounds__(256, 1)
k2_select_sum(const int* __restrict__ lab, uint32_t* __restrict__ gws,
              const float* __restrict__ Dm, float* __restrict__ out) {
    uint32_t* ghA  = gws;
    uint32_t* gCnt = gws + 2048;
    uint64_t* part = (uint64_t*)(gws + 2050);
    uint32_t* gF2  = gws + 2562;
    uint32_t* buf  = gws + 2820;

    __shared__ uint32_t sh[2048];                 // select copy / finalizer hist
    __shared__ unsigned long long ssum[2048];
    __shared__ float    sD[B];
    __shared__ int      sL[B];
    __shared__ float    pbase[PMAX];
    __shared__ int      wcnt[4];
    __shared__ uint32_t wtot[4];
    __shared__ uint32_t res[2];
    __shared__ unsigned long long usum[4];
    __shared__ unsigned long long sAcc2;
    __shared__ uint32_t sBase;

    const int q = blockIdx.x, tid = threadIdx.x;
    const int lane = tid & 63, wv = tid >> 6;

    // disarm init flag for the next graph replay (k1 re-arms it)
    if (q == 0 && tid == 0)
        __hip_atomic_store((uint64_t*)(gws + 2818), 0ull,
                           __ATOMIC_RELAXED, SC_AGENT);

    // reload D row + labels; copy ghA to LDS with plain cached loads
    sD[tid] = Dm[q * B + tid];
    sL[tid] = lab[tid];
    for (int i = tid; i < 2048; i += 256) sh[i] = ghA[i];
    __syncthreads();
    const int pcnt = compact_pos(sD, sL, pbase, wcnt, q, tid, lane, wv);
    __syncthreads();
    const bool  nvalid = (sL[tid] != sL[q]);
    const float dqn    = sD[tid];

    // select of s0 (redundant per block, on LDS copy)
    selstep<8>(sh, (uint32_t)TOPK, wtot, res, tid);
    const uint32_t s0      = res[0];
    const uint32_t needed0 = res[1];

    // phase 2: register sum above s0 + append in-bucket values
    uint64_t sumA = 0;
    uint32_t cin  = 0;
    if (nvalid) {
        for (int ip = 0; ip < pcnt; ++ip) {
            const float v = fmaxf(pbase[ip] - dqn, 0.0f);
            const uint32_t bk = __float_as_uint(v) >> 21;
            if (bk > s0) sumA += fixv(v);
            else if (bk == s0) ++cin;
        }
    }
    {
        uint32_t inc = cin;
#pragma unroll
        for (int d = 1; d < 64; d <<= 1) {
            uint32_t t2 = __shfl_up(inc, d, 64);
            if (lane >= d) inc += t2;
        }
        if (lane == 63) wtot[wv] = inc;
        __syncthreads();
        uint32_t woff = 0;
        for (int w = 0; w < wv; ++w) woff += wtot[w];
        const uint32_t myoff = woff + inc - cin;
        if (tid == 0) {
            const uint32_t tot = wtot[0] + wtot[1] + wtot[2] + wtot[3];
            sBase = tot ? atomicAdd(gCnt, tot) : 0u;
        }
        __syncthreads();
        if (cin) {
            uint32_t o = sBase + myoff;
            for (int ip = 0; ip < pcnt; ++ip) {
                const uint32_t bits =
                    __float_as_uint(fmaxf(pbase[ip] - dqn, 0.0f));
                if ((bits >> 21) == s0) {
                    if (o < BUFCAP) st_rlx32(&buf[o], bits);
                    ++o;
                }
            }
        }
    }
    // block-reduce sumA -> per-block relaxed store (no RMW train)
#pragma unroll
    for (int off = 32; off > 0; off >>= 1)
        sumA += __shfl_down((unsigned long long)sumA, off, 64);
    if (lane == 0) usum[wv] = sumA;
    __syncthreads();
    if (tid == 0)
        st_rlx64(&part[q], (uint64_t)(usum[0] + usum[1] + usum[2] + usum[3]));
    __syncthreads();   // drain all waves' buf/part stores before flag
    if (tid == 0)
        __hip_atomic_store(&gF2[q], 1u, __ATOMIC_RELEASE, SC_AGENT);
    if (q != B - 1) return;          // 255 blocks exit; block 255 finalizes

    // ---------------- finalizer (block 255) ----------------
    // wait for all blocks' done-flags (acquire -> their buf/part visible)
    for (;;) {
        const uint32_t f = __hip_atomic_load(&gF2[tid], __ATOMIC_ACQUIRE, SC_AGENT);
        if (__syncthreads_count(f != 0) == B) break;
        __builtin_amdgcn_s_sleep(2);
    }

    const uint32_t nbuf = min(ld_rlx32(gCnt), BUFCAP);

    // sum of all per-block partials (integer, order-free)
    {
        uint64_t pv = ld_rlx64(&part[tid]);
#pragma unroll
        for (int off = 32; off > 0; off >>= 1)
            pv += __shfl_down((unsigned long long)pv, off, 64);
        if (lane == 0) usum[wv] = pv;
        __syncthreads();
        if (tid == 0) sAcc2 = usum[0] + usum[1] + usum[2] + usum[3];
    }
    __syncthreads();
    const uint64_t sumAbove = sAcc2;
    __syncthreads();

    // level 2: bits[20:10] count+sum hists from buf
    for (int i = tid; i < 2048; i += 256) { sh[i] = 0; ssum[i] = 0ull; }
    __syncthreads();
    for (uint32_t i = (uint32_t)tid; i < nbuf; i += 256) {
        const uint32_t b = ld_rlx32(&buf[i]);
        const uint32_t b2 = (b >> 10) & 0x7FFu;
        atomicAdd(&sh[b2], 1u);
        atomicAdd(&ssum[b2], (unsigned long long)fixv(__uint_as_float(b)));
    }
    __syncthreads();
    selstep<8>(sh, needed0, wtot, res, tid);
    const uint32_t s1      = res[0];
    const uint32_t needed1 = res[1];
    {
        uint64_t sb = 0;
#pragma unroll
        for (int k = 0; k < 8; ++k) {
            const uint32_t b = (uint32_t)tid * 8u + (uint32_t)k;
            if (b > s1) sb += ssum[b];
        }
#pragma unroll
        for (int off = 32; off > 0; off >>= 1)
            sb += __shfl_down((unsigned long long)sb, off, 64);
        if (lane == 0) usum[wv] = sb;
        __syncthreads();
        if (tid == 0) sAcc2 = usum[0] + usum[1] + usum[2] + usum[3];
    }
    __syncthreads();
    const uint64_t sumL2 = sAcc2;
    __syncthreads();

    // level 3: bits[9:0] within (s0,s1)
    for (int i = tid; i < 1024; i += 256) { sh[i] = 0; ssum[i] = 0ull; }
    __syncthreads();
    for (uint32_t i = (uint32_t)tid; i < nbuf; i += 256) {
        const uint32_t b = ld_rlx32(&buf[i]);
        if (((b >> 10) & 0x7FFu) == s1) {
            const uint32_t b3 = b & 0x3FFu;
            atomicAdd(&sh[b3], 1u);
            atomicAdd(&ssum[b3], (unsigned long long)fixv(__uint_as_float(b)));
        }
    }
    __syncthreads();
    selstep<4>(sh, needed1, wtot, res, tid);
    const uint32_t s2      = res[0];
    const uint32_t needed2 = res[1];
    const uint32_t T = (s0 << 21) | (s1 << 10) | s2;
    {
        uint64_t sb = 0;
#pragma unroll
        for (int k = 0; k < 4; ++k) {
            const uint32_t b = (uint32_t)tid * 4u + (uint32_t)k;
            if (b > s2) sb += ssum[b];
        }
#pragma unroll
        for (int off = 32; off > 0; off >>= 1)
            sb += __shfl_down((unsigned long long)sb, off, 64);
        if (lane == 0) usum[wv] = sb;
        __syncthreads();
        if (tid == 0) {
            const uint64_t total =
                usum[0] + usum[1] + usum[2] + usum[3] + sumL2 + sumAbove;
            const double tval = (double)__uint_as_float(T);
            const double loss = ((double)total * (1.0 / FIX_SCALE) +
                                 (double)needed2 * tval) / (double)TOPK;
            out[0] = (float)loss;
        }
    }
}

extern "C" void kernel_launch(void* const* d_in, const int* in_sizes, int n_in,
                              void* d_out, int out_size, void* d_ws, size_t ws_size,
                              hipStream_t stream) {
    const float* x   = (const float*)d_in[0];
    const int*   lab = (const int*)d_in[1];
    float*       out = (float*)d_out;
    uint32_t*    gws = (uint32_t*)d_ws;
    float*       Dm  = (float*)((char*)d_ws + 262144);

    k1_dist_hist<<<B, 256, 0, stream>>>(x, lab, gws, Dm);
    k2_select_sum<<<B, 256, 0, stream>>>(lab, gws, Dm, out);
}